// Round 4
// baseline (326.126 us; speedup 1.0000x reference)
//
#include <hip/hip_runtime.h>

// B = 512 (vector length), F = 2048 (features). One block per feature.
// out[f] = sum_i W2[f,i] * lrelu( sum_j W1[f,i,j] * x[j,f] + b1[f,i] ) + b2[f]
// Memory-bound on the single streaming read of W1 (2 GiB).
// R4: (a) rows interleaved across waves (i = 4r + wave) so each block's
//     concurrent loads form one contiguous 8KB chunk -> DRAM page locality;
//     (b) pre-transpose x into d_ws so block startup reads are coalesced.

#define BB 512
#define FF 2048

typedef float f32x4 __attribute__((ext_vector_type(4)));

__global__ __launch_bounds__(256) void xpose_kernel(
    const float* __restrict__ x,  // [B, F]
    float* __restrict__ xt)       // [F, B]
{
    // coalesced read along f; strided write (4 MB total, trivial)
    int idx = blockIdx.x * 256 + threadIdx.x;      // idx = b*FF + f
    int b = idx >> 11;                              // / 2048
    int f = idx & (FF - 1);
    xt[(size_t)f * BB + b] = x[idx];
}

template <bool XT>
__global__ __launch_bounds__(256) void tdisc_kernel(
    const float* __restrict__ x,   // [B, F] or xt [F, B] when XT
    const float* __restrict__ W1,  // [F, B, B]
    const float* __restrict__ b1,  // [F, B]
    const float* __restrict__ W2,  // [F, B]
    const float* __restrict__ b2,  // [F]
    float* __restrict__ out)       // [F]
{
    const int f = blockIdx.x;
    __shared__ float xs[BB];
    __shared__ float b1s[BB];
    __shared__ float w2s[BB];
    __shared__ float wpart[4];

    const int tid = threadIdx.x;

    for (int t = tid; t < BB; t += 256) {
        xs[t]  = XT ? x[(size_t)f * BB + t]      // coalesced pre-transposed
                    : x[(size_t)t * FF + f];     // strided gather fallback
        b1s[t] = b1[(size_t)f * BB + t];
        w2s[t] = W2[(size_t)f * BB + t];
    }
    __syncthreads();

    const int wave = tid >> 6;
    const int lane = tid & 63;

    const f32x4* __restrict__ W1f =
        (const f32x4*)(W1 + (size_t)f * BB * BB);
    const f32x4* xs4 = (const f32x4*)xs;

    // Row-invariant x fragments: lane l covers j = 4l..4l+3 and 256+4l..256+4l+3
    const f32x4 xv0 = xs4[lane];
    const f32x4 xv1 = xs4[lane + 64];

    float partial = 0.0f;

    #pragma unroll 8
    for (int r = 0; r < 128; ++r) {
        const int i = (r << 2) | wave;  // waves interleaved: contiguous 8KB/instant
        const f32x4* row = W1f + (size_t)i * (BB / 4);
        // 2 x 1KB coalesced wave loads of W1 row i, streaming (nt: bypass L2)
        f32x4 w0 = __builtin_nontemporal_load(row + lane);
        f32x4 w1 = __builtin_nontemporal_load(row + lane + 64);
        float s = w0.x * xv0.x + w0.y * xv0.y + w0.z * xv0.z + w0.w * xv0.w
                + w1.x * xv1.x + w1.y * xv1.y + w1.z * xv1.z + w1.w * xv1.w;
        // 64-lane butterfly reduce -> full dot product in every lane
        #pragma unroll
        for (int off = 32; off >= 1; off >>= 1)
            s += __shfl_xor(s, off, 64);
        float h = s + b1s[i];
        h = (h >= 0.0f) ? h : 0.2f * h;          // leaky_relu(0.2)
        partial = fmaf(w2s[i], h, partial);      // same value in all lanes
    }

    if (lane == 0) wpart[wave] = partial;
    __syncthreads();
    if (tid == 0)
        out[f] = wpart[0] + wpart[1] + wpart[2] + wpart[3] + b2[f];
}

extern "C" void kernel_launch(void* const* d_in, const int* in_sizes, int n_in,
                              void* d_out, int out_size, void* d_ws, size_t ws_size,
                              hipStream_t stream) {
    const float* x  = (const float*)d_in[0];
    const float* W1 = (const float*)d_in[1];
    const float* b1 = (const float*)d_in[2];
    const float* W2 = (const float*)d_in[3];
    const float* b2 = (const float*)d_in[4];
    float* out = (float*)d_out;

    const size_t xbytes = (size_t)BB * FF * sizeof(float);
    if (ws_size >= xbytes) {
        float* xt = (float*)d_ws;
        xpose_kernel<<<(BB * FF) / 256, 256, 0, stream>>>(x, xt);
        tdisc_kernel<true><<<FF, 256, 0, stream>>>(xt, W1, b1, W2, b2, out);
    } else {
        tdisc_kernel<false><<<FF, 256, 0, stream>>>(x, W1, b1, W2, b2, out);
    }
}

// Round 5
// 323.524 us; speedup vs baseline: 1.0080x; 1.0080x over previous
//
#include <hip/hip_runtime.h>

// B = 512 (vector length), F = 2048 (features). One block per feature.
// out[f] = sum_i W2[f,i] * lrelu( sum_j W1[f,i,j] * x[j,f] + b1[f,i] ) + b2[f]
// Memory-bound on the single streaming read of W1 (2 GiB).
// FINAL (= R3 best variant, 323.6 us = 6.67 TB/s effective read stream):
//   - one block (4 waves) per feature; x/b1/W2 staged in LDS
//   - 2x 1KB coalesced nontemporal float4 wave loads per W1 row
//   - unroll 8 for ~16 loads in flight per wave
//   - 64-lane butterfly reduce per row; f32 accumulation throughout
// R4 nulls (reverted): wave-interleaved rows, x pre-transpose -> both within
// noise; DRAM page locality already optimal.

#define BB 512
#define FF 2048

typedef float f32x4 __attribute__((ext_vector_type(4)));

__global__ __launch_bounds__(256) void tdisc_kernel(
    const float* __restrict__ x,   // [B, F]
    const float* __restrict__ W1,  // [F, B, B]
    const float* __restrict__ b1,  // [F, B]
    const float* __restrict__ W2,  // [F, B]
    const float* __restrict__ b2,  // [F]
    float* __restrict__ out)       // [F]
{
    const int f = blockIdx.x;
    __shared__ float xs[BB];
    __shared__ float b1s[BB];
    __shared__ float w2s[BB];
    __shared__ float wpart[4];

    const int tid = threadIdx.x;

    // Stage per-feature vectors into LDS. x is strided (stride F) but tiny
    // (4 MB total across all blocks -> L2/L3 resident; nt on W1 keeps it so).
    for (int t = tid; t < BB; t += 256) {
        xs[t]  = x[(size_t)t * FF + f];
        b1s[t] = b1[(size_t)f * BB + t];
        w2s[t] = W2[(size_t)f * BB + t];
    }
    __syncthreads();

    const int wave = tid >> 6;
    const int lane = tid & 63;

    const f32x4* __restrict__ W1f =
        (const f32x4*)(W1 + (size_t)f * BB * BB);
    const f32x4* xs4 = (const f32x4*)xs;

    // Row-invariant x fragments: lane l covers j = 4l..4l+3 and 256+4l..256+4l+3
    const f32x4 xv0 = xs4[lane];
    const f32x4 xv1 = xs4[lane + 64];

    float partial = 0.0f;
    const int row0 = wave * 128;  // 4 waves x 128 rows = 512 rows

    #pragma unroll 8
    for (int r = 0; r < 128; ++r) {
        const int i = row0 + r;
        const f32x4* row = W1f + (size_t)i * (BB / 4);
        // 2 x 1KB coalesced wave loads of W1 row i, streaming (nt: bypass L2)
        f32x4 w0 = __builtin_nontemporal_load(row + lane);
        f32x4 w1 = __builtin_nontemporal_load(row + lane + 64);
        float s = w0.x * xv0.x + w0.y * xv0.y + w0.z * xv0.z + w0.w * xv0.w
                + w1.x * xv1.x + w1.y * xv1.y + w1.z * xv1.z + w1.w * xv1.w;
        // 64-lane butterfly reduce -> full dot product in every lane
        #pragma unroll
        for (int off = 32; off >= 1; off >>= 1)
            s += __shfl_xor(s, off, 64);
        float h = s + b1s[i];
        h = (h >= 0.0f) ? h : 0.2f * h;          // leaky_relu(0.2)
        partial = fmaf(w2s[i], h, partial);      // same value in all lanes
    }

    if (lane == 0) wpart[wave] = partial;
    __syncthreads();
    if (tid == 0)
        out[f] = wpart[0] + wpart[1] + wpart[2] + wpart[3] + b2[f];
}

extern "C" void kernel_launch(void* const* d_in, const int* in_sizes, int n_in,
                              void* d_out, int out_size, void* d_ws, size_t ws_size,
                              hipStream_t stream) {
    const float* x  = (const float*)d_in[0];
    const float* W1 = (const float*)d_in[1];
    const float* b1 = (const float*)d_in[2];
    const float* W2 = (const float*)d_in[3];
    const float* b2 = (const float*)d_in[4];
    float* out = (float*)d_out;

    tdisc_kernel<<<FF, 256, 0, stream>>>(x, W1, b1, W2, b2, out);
}